// Round 21
// baseline (462.676 us; speedup 1.0000x reference)
//
#include <hip/hip_runtime.h>
#include <math.h>

#define C_CAP 1000000
#define DIM 64

// ws layout (floats)
#define SCORES_OFF 0          // [1,000,000] scores
#define P1_OFF     1000000    // per-block pairs {m, l}, stride 4, NB1 blocks (2048*4=8192 < 10000 pad)
#define HDR_OFF    1010000    // [0]=M, [1]=L_shift, [2]=argmax (int bits)
#define ACC_OFF    1010064    // [64] atomic accumulator

#define NB1 2048              // K1 grid: 8 blocks/CU, 32 waves/CU (factorial cell: 32w x nt)
#define NW1 (NB1 * 4)
#define NTILES (C_CAP / 16)   // 62500: 16 rows per wave-iteration in K1
#define NB3 2048
#define NW3 (NB3 * 4)
#define NCHUNKS (C_CAP / 64)  // 15625

// ext_vector float4 so __builtin_nontemporal_load accepts it.
typedef float f4 __attribute__((ext_vector_type(4)));

// ---------------------------------------------------------------------------
// K1: lean 32-waves/CU + NON-TEMPORAL key loads.
// Factorial history: (16w, no-nt)=~105us [R3], (32w, no-nt)=~105-110 [R7 null],
// (16w, nt)=~83us [R19 win, -22us]. This round measures the last cell
// (32w, nt): nt removed the L2/L3 allocation throttle; if the residual cap is
// outstanding-miss count scaling with waves/CU, TLP now composes -> ~55-65us.
// Lean single-buffer structure (R7) to fit the 64-VGPR budget at 8 waves/EU
// (dbuf's 8xfloat4 = 32 VGPR would risk spill; dbuf measured null anyway).
// Lane layout per 16-row (4 KB) tile: load j covers rows 16t+4j+g (g=lane>>4),
// cl=lane&15 owns cols 4cl..4cl+3; butterfly-reduce; cl<4 stores 16 scores
// (one contiguous 64 B segment per tile). l = UNSHIFTED sum(exp(s)), fp32-safe.
// ---------------------------------------------------------------------------
__global__ __launch_bounds__(256, 8) void nd_scores(
    const float* __restrict__ query,
    const float* __restrict__ keys,
    float* __restrict__ ws, int ntiles, int stride)
{
    const int tid  = threadIdx.x;
    const int lane = tid & 63;
    const int wave = tid >> 6;
    const int cl   = lane & 15;
    const int g    = lane >> 4;
    const int wglobal = blockIdx.x * 4 + wave;

    const float4 q4 = ((const float4*)query)[cl];
    const f4* __restrict__ k4p = (const f4*)keys;

    float m = -1e30f, l = 0.f;

    for (int t = wglobal; t < ntiles; t += stride) {
        const f4* __restrict__ kp = k4p + (size_t)t * 256 + lane;
        const f4 k0 = __builtin_nontemporal_load(kp);
        const f4 k1 = __builtin_nontemporal_load(kp + 64);
        const f4 k2 = __builtin_nontemporal_load(kp + 128);
        const f4 k3 = __builtin_nontemporal_load(kp + 192);

        float s0 = fmaf(k0.x, q4.x, fmaf(k0.y, q4.y, fmaf(k0.z, q4.z, k0.w * q4.w)));
        float s1 = fmaf(k1.x, q4.x, fmaf(k1.y, q4.y, fmaf(k1.z, q4.z, k1.w * q4.w)));
        float s2 = fmaf(k2.x, q4.x, fmaf(k2.y, q4.y, fmaf(k2.z, q4.z, k2.w * q4.w)));
        float s3 = fmaf(k3.x, q4.x, fmaf(k3.y, q4.y, fmaf(k3.z, q4.z, k3.w * q4.w)));

        // 4 interleaved 4-step butterflies (16-lane dot reduction)
        s0 += __shfl_xor(s0, 1); s1 += __shfl_xor(s1, 1);
        s2 += __shfl_xor(s2, 1); s3 += __shfl_xor(s3, 1);
        s0 += __shfl_xor(s0, 2); s1 += __shfl_xor(s1, 2);
        s2 += __shfl_xor(s2, 2); s3 += __shfl_xor(s3, 2);
        s0 += __shfl_xor(s0, 4); s1 += __shfl_xor(s1, 4);
        s2 += __shfl_xor(s2, 4); s3 += __shfl_xor(s3, 4);
        s0 += __shfl_xor(s0, 8); s1 += __shfl_xor(s1, 8);
        s2 += __shfl_xor(s2, 8); s3 += __shfl_xor(s3, 8);

        const float sv = (cl == 0) ? s0 : (cl == 1) ? s1 : (cl == 2) ? s2 : s3;
        if (cl < 4) ws[SCORES_OFF + t * 16 + 4 * cl + g] = sv;

        l += (__expf(s0) + __expf(s1)) + (__expf(s2) + __expf(s3));
        m = fmaxf(m, fmaxf(fmaxf(s0, s1), fmaxf(s2, s3)));
    }

    // combine the 4 16-lane groups inside the wave
    l += __shfl_xor(l, 16); m = fmaxf(m, __shfl_xor(m, 16));
    l += __shfl_xor(l, 32); m = fmaxf(m, __shfl_xor(m, 32));

    __shared__ float s_m[4], s_l[4];
    if (lane == 0) { s_m[wave] = m; s_l[wave] = l; }
    __syncthreads();
    if (tid == 0) {
        float bm = s_m[0], bl = s_l[0];
        #pragma unroll
        for (int wv = 1; wv < 4; ++wv) {
            bl += s_l[wv];
            bm = fmaxf(bm, s_m[wv]);
        }
        float* bp = ws + P1_OFF + (size_t)blockIdx.x * 4;
        bp[0] = bm;
        bp[1] = bl;
    }
}

// ---------------------------------------------------------------------------
// K2: single block. Reduce per-block pairs -> M, L_shift; zero ACC. (R3)
// ---------------------------------------------------------------------------
__global__ __launch_bounds__(256) void nd_reduce(float* __restrict__ ws, int nb)
{
    const int tid = threadIdx.x;
    float m = -1e30f, l = 0.f;
    for (int b = tid; b < nb; b += 256) {
        const float* bp = ws + P1_OFF + (size_t)b * 4;
        l += bp[1];
        m = fmaxf(m, bp[0]);
    }
    __shared__ float sm[256], sl[256];
    sm[tid] = m; sl[tid] = l;
    __syncthreads();
    for (int s = 128; s > 0; s >>= 1) {
        if (tid < s) {
            sl[tid] += sl[tid + s];
            sm[tid] = fmaxf(sm[tid], sm[tid + s]);
        }
        __syncthreads();
    }
    if (tid == 0) {
        const float M = sm[0];
        ws[HDR_OFF + 0] = M;
        ws[HDR_OFF + 1] = sl[0] * __expf(-M);   // L_shift = sum(exp(s-M))
        ((int*)ws)[HDR_OFF + 2] = 0;
    }
    if (tid < 64) ws[ACC_OFF + tid] = 0.f;
}

// ---------------------------------------------------------------------------
// K3: selective P.V + argmax via s == M bit-equality. (R3, unchanged)
// ---------------------------------------------------------------------------
__global__ __launch_bounds__(256, 8) void nd_pv(
    const float* __restrict__ values,
    float* __restrict__ ws, int nchunks, int nwaves_total)
{
    const int tid  = threadIdx.x;
    const int lane = tid & 63;
    const int wave = tid >> 6;
    const int wglobal = blockIdx.x * 4 + wave;

    const float M   = ws[HDR_OFF];
    const float thr = M - 23.0f;
    float acc = 0.f;

    for (int c = wglobal; c < nchunks; c += nwaves_total) {
        const float s = ws[SCORES_OFF + (size_t)c * 64 + lane];
        unsigned long long mask = __ballot(s > thr);
        if (mask) {
            if (s == M) ((int*)ws)[HDR_OFF + 2] = c * 64 + lane;
            const float w = __expf(s - M);
            while (mask) {
                const int b = __ffsll((long long)mask) - 1;
                mask &= mask - 1;
                const float wb = __shfl(w, b);
                acc = fmaf(wb, values[(size_t)(c * 64 + b) * 64 + lane], acc);
            }
        }
    }

    __shared__ float sA[4][64];
    sA[wave][lane] = acc;
    __syncthreads();
    if (tid < 64) {
        const float v = sA[0][tid] + sA[1][tid] + sA[2][tid] + sA[3][tid];
        if (v != 0.f) atomicAdd(ws + ACC_OFF + tid, v);
    }
}

// ---------------------------------------------------------------------------
// K4: finalize. (R3, unchanged)
// ---------------------------------------------------------------------------
__global__ __launch_bounds__(128) void nd_final(
    const float* __restrict__ ws, float* __restrict__ out)
{
    const int tid = threadIdx.x;
    if (tid < 64) out[tid] = ws[ACC_OFF + tid] / ws[HDR_OFF + 1];
    if (tid == 64) out[64] = (float)((const int*)ws)[HDR_OFF + 2];
}

extern "C" void kernel_launch(void* const* d_in, const int* in_sizes, int n_in,
                              void* d_out, int out_size, void* d_ws, size_t ws_size,
                              hipStream_t stream) {
    const float* query  = (const float*)d_in[0];
    const float* keys   = (const float*)d_in[1];
    const float* values = (const float*)d_in[2];
    float* out = (float*)d_out;
    float* ws  = (float*)d_ws;

    nd_scores<<<NB1, 256, 0, stream>>>(query, keys, ws, NTILES, NW1);
    nd_reduce<<<1, 256, 0, stream>>>(ws, NB1);
    nd_pv<<<NB3, 256, 0, stream>>>(values, ws, NCHUNKS, NW3);
    nd_final<<<1, 128, 0, stream>>>(ws, out);
}